// Round 16
// baseline (837.706 us; speedup 1.0000x reference)
//
#include <hip/hip_runtime.h>
#include <hip/hip_bf16.h>
#include <cstdint>
#include <cstddef>

using bf16 = __hip_bfloat16;
typedef __attribute__((ext_vector_type(8))) short bf16x8;
typedef __attribute__((ext_vector_type(4))) float f32x4;

#define DEVINL __device__ __forceinline__

constexpr int TOK = 9232;   // 16*577
constexpr int TP  = 9344;   // 73*128
constexpr int NPAD = 640;   // key padding (10*64)

DEVINL unsigned short f2bu(float x) {
  union { bf16 h; unsigned short u; } cv; cv.h = __float2bfloat16(x); return cv.u;
}

DEVINL void gload_lds16(const void* g, void* l) {
  __builtin_amdgcn_global_load_lds((const __attribute__((address_space(1))) void*)g,
                                   (__attribute__((address_space(3))) void*)l, 16, 0, 0);
}

// ---------------- block reduce helper (NV values across 256 threads) --------
template <int NV>
DEVINL void blk_reduce(float* v, float* lds, int tid) {
  const int lane = tid & 63, wv = tid >> 6;
  #pragma unroll
  for (int k = 0; k < NV; ++k) {
    float x = v[k];
    x += __shfl_xor(x, 1);  x += __shfl_xor(x, 2);  x += __shfl_xor(x, 4);
    x += __shfl_xor(x, 8);  x += __shfl_xor(x, 16); x += __shfl_xor(x, 32);
    v[k] = x;
  }
  if (lane == 0) {
    #pragma unroll
    for (int k = 0; k < NV; ++k) lds[wv * NV + k] = v[k];
  }
  __syncthreads();
  #pragma unroll
  for (int k = 0; k < NV; ++k)
    v[k] = lds[k] + lds[NV + k] + lds[2 * NV + k] + lds[3 * NV + k];
  __syncthreads();
}

// ---------------- weight prep ------------------------------------------------
__global__ void prep_cast(const float* __restrict__ s, bf16* __restrict__ d, int n) {
  int i = blockIdx.x * 256 + threadIdx.x;
  if (i < n) d[i] = __float2bfloat16(s[i]);
}
// W1 aug: [4608][1024]; rows 4096+ = ad_down[e][d][bn] (row j=e*64+bn)
__global__ void prep_w1(const float* __restrict__ fc1_w, const float* __restrict__ ad_down,
                        bf16* __restrict__ W) {
  int i = blockIdx.x * 256 + threadIdx.x;
  if (i >= 4608 * 1024) return;
  int row = i >> 10, d = i & 1023;
  float v;
  if (row < 4096) v = fc1_w[(size_t)row * 1024 + d];
  else { int j = row - 4096; v = ad_down[((size_t)(j >> 6) * 1024 + d) * 64 + (j & 63)]; }
  W[i] = __float2bfloat16(v);
}
// W2 aug: [1024][4608]; cols 4096+ = ad_up[e][bn][d] (col j=e*64+bn)
__global__ void prep_w2(const float* __restrict__ fc2_w, const float* __restrict__ ad_up,
                        bf16* __restrict__ W) {
  int i = blockIdx.x * 256 + threadIdx.x;
  if (i >= 1024 * 4608) return;
  int d = i / 4608, c = i - d * 4608;
  float v;
  if (c < 4096) v = fc2_w[(size_t)d * 4096 + c];
  else { int j = c - 4096; v = ad_up[((size_t)(j >> 6) * 64 + (j & 63)) * 1024 + d]; }
  W[i] = __float2bfloat16(v);
}

// ---------------- LN1 + top2 gates + LoRA h -> n1 [TP,1024], tfF/tfI --------
// tfF layout [TOK][20]: [0]=w0 [1]=w1 [4..11]=h0 [12..19]=h1 (16B-aligned h)
__global__ __launch_bounds__(256)
void ln1_kernel(const float* __restrict__ tokens, const float* __restrict__ gw,
                const float* __restrict__ bw, const float* __restrict__ lgate,
                const float* __restrict__ lora_a, bf16* __restrict__ n1,
                float* __restrict__ tfF, int* __restrict__ tfI) {
  __shared__ float lred[64];
  __shared__ float sW[2];
  __shared__ int sI[2];
  const int t = blockIdx.x, tid = threadIdx.x;
  bf16* outr = n1 + (size_t)t * 1024;
  if (t >= TOK) {
    ((ushort4*)outr)[tid] = make_ushort4(0, 0, 0, 0);
    return;
  }
  const float4 x = ((const float4*)(tokens + (size_t)t * 1024))[tid];
  float v2[2] = { x.x + x.y + x.z + x.w, x.x * x.x + x.y * x.y + x.z * x.z + x.w * x.w };
  blk_reduce<2>(v2, lred, tid);
  const float mean = v2[0] * (1.f / 1024.f);
  const float var  = v2[1] * (1.f / 1024.f) - mean * mean;
  const float rstd = rsqrtf(var + 1e-6f);
  const float4 gg = ((const float4*)gw)[tid];
  const float4 bb = ((const float4*)bw)[tid];
  float nv[4] = { (x.x - mean) * rstd * gg.x + bb.x, (x.y - mean) * rstd * gg.y + bb.y,
                  (x.z - mean) * rstd * gg.z + bb.z, (x.w - mean) * rstd * gg.w + bb.w };
  ((ushort4*)outr)[tid] = make_ushort4(f2bu(nv[0]), f2bu(nv[1]), f2bu(nv[2]), f2bu(nv[3]));
  const int d0 = tid * 4;
  float lg[8] = {0, 0, 0, 0, 0, 0, 0, 0};
  {
    const float4* gp = (const float4*)(lgate + (size_t)d0 * 8);
    #pragma unroll
    for (int dd = 0; dd < 4; ++dd) {
      const float4 a = gp[dd * 2], c = gp[dd * 2 + 1];
      const float nd = nv[dd];
      lg[0] += nd * a.x; lg[1] += nd * a.y; lg[2] += nd * a.z; lg[3] += nd * a.w;
      lg[4] += nd * c.x; lg[5] += nd * c.y; lg[6] += nd * c.z; lg[7] += nd * c.w;
    }
  }
  blk_reduce<8>(lg, lred, tid);
  if (tid == 0) {
    float b0 = -1e30f; int i0 = 0;
    #pragma unroll
    for (int e = 0; e < 8; ++e) if (lg[e] > b0) { b0 = lg[e]; i0 = e; }
    float b1 = -1e30f; int i1 = 0;
    #pragma unroll
    for (int e = 0; e < 8; ++e) if (e != i0 && lg[e] > b1) { b1 = lg[e]; i1 = e; }
    const float e1 = __expf(b1 - b0);
    const float inv = 1.f / (1.f + e1);
    sW[0] = inv; sW[1] = e1 * inv; sI[0] = i0; sI[1] = i1;
  }
  __syncthreads();
  const int e0 = sI[0], e1i = sI[1];
  float hv[16];
  #pragma unroll
  for (int k = 0; k < 16; ++k) hv[k] = 0.f;
  #pragma unroll
  for (int ei = 0; ei < 2; ++ei) {
    const float* Ae = lora_a + (size_t)(ei == 0 ? e0 : e1i) * 8192;
    #pragma unroll
    for (int dd = 0; dd < 4; ++dd) {
      const float4* ap = (const float4*)(Ae + (size_t)(d0 + dd) * 8);
      const float4 a = ap[0], c = ap[1];
      const float nd = nv[dd];
      hv[ei * 8 + 0] += nd * a.x; hv[ei * 8 + 1] += nd * a.y;
      hv[ei * 8 + 2] += nd * a.z; hv[ei * 8 + 3] += nd * a.w;
      hv[ei * 8 + 4] += nd * c.x; hv[ei * 8 + 5] += nd * c.y;
      hv[ei * 8 + 6] += nd * c.z; hv[ei * 8 + 7] += nd * c.w;
    }
  }
  blk_reduce<16>(hv, lred, tid);
  if (tid == 0) {
    tfI[t * 2] = e0; tfI[t * 2 + 1] = e1i;
    tfF[(size_t)t * 20] = sW[0]; tfF[(size_t)t * 20 + 1] = sW[1];
  }
  if (tid < 16) tfF[(size_t)t * 20 + 4 + tid] = hv[tid];
}

// ---------------- LN2 + top2 adapter gates -> mi [TP,1024], dense g2 --------
__global__ __launch_bounds__(256)
void ln2_kernel(const float* __restrict__ tok2, const float* __restrict__ gw,
                const float* __restrict__ bw, const float* __restrict__ agate,
                bf16* __restrict__ mi, float* __restrict__ g2) {
  __shared__ float lred[64];
  __shared__ float sW[2];
  __shared__ int sI[2];
  const int t = blockIdx.x, tid = threadIdx.x;
  bf16* outr = mi + (size_t)t * 1024;
  if (t >= TOK) {
    ((ushort4*)outr)[tid] = make_ushort4(0, 0, 0, 0);
    return;
  }
  const float4 x = ((const float4*)(tok2 + (size_t)t * 1024))[tid];
  float v2[2] = { x.x + x.y + x.z + x.w, x.x * x.x + x.y * x.y + x.z * x.z + x.w * x.w };
  blk_reduce<2>(v2, lred, tid);
  const float mean = v2[0] * (1.f / 1024.f);
  const float var  = v2[1] * (1.f / 1024.f) - mean * mean;
  const float rstd = rsqrtf(var + 1e-6f);
  const float4 gg = ((const float4*)gw)[tid];
  const float4 bb = ((const float4*)bw)[tid];
  float nv[4] = { (x.x - mean) * rstd * gg.x + bb.x, (x.y - mean) * rstd * gg.y + bb.y,
                  (x.z - mean) * rstd * gg.z + bb.z, (x.w - mean) * rstd * gg.w + bb.w };
  ((ushort4*)outr)[tid] = make_ushort4(f2bu(nv[0]), f2bu(nv[1]), f2bu(nv[2]), f2bu(nv[3]));
  const int d0 = tid * 4;
  float lg[8] = {0, 0, 0, 0, 0, 0, 0, 0};
  {
    const float4* gp = (const float4*)(agate + (size_t)d0 * 8);
    #pragma unroll
    for (int dd = 0; dd < 4; ++dd) {
      const float4 a = gp[dd * 2], c = gp[dd * 2 + 1];
      const float nd = nv[dd];
      lg[0] += nd * a.x; lg[1] += nd * a.y; lg[2] += nd * a.z; lg[3] += nd * a.w;
      lg[4] += nd * c.x; lg[5] += nd * c.y; lg[6] += nd * c.z; lg[7] += nd * c.w;
    }
  }
  blk_reduce<8>(lg, lred, tid);
  if (tid == 0) {
    float b0 = -1e30f; int i0 = 0;
    #pragma unroll
    for (int e = 0; e < 8; ++e) if (lg[e] > b0) { b0 = lg[e]; i0 = e; }
    float b1 = -1e30f; int i1 = 0;
    #pragma unroll
    for (int e = 0; e < 8; ++e) if (e != i0 && lg[e] > b1) { b1 = lg[e]; i1 = e; }
    const float e1 = __expf(b1 - b0);
    const float inv = 1.f / (1.f + e1);
    sW[0] = inv; sW[1] = e1 * inv; sI[0] = i0; sI[1] = i1;
  }
  __syncthreads();
  if (tid < 8) {
    float gv = 0.f;
    if (tid == sI[0]) gv = sW[0];
    else if (tid == sI[1]) gv = sW[1];
    g2[(size_t)t * 8 + tid] = gv;
  }
}

// ---------------- 128x128 bf16 NT GEMM (m97 structure) ----------------------
template <class Epi>
__global__ __launch_bounds__(256)
void gemm_nt(const bf16* __restrict__ A, const bf16* __restrict__ B, int K, Epi epi) {
  __shared__ __align__(16) bf16 lA[128 * 64];
  __shared__ __align__(16) bf16 lB[128 * 64];
  const int tid = threadIdx.x;
  const int lane = tid & 63, wv = tid >> 6;
  const int mt = blockIdx.y, nt = blockIdx.x;
  const int wr = wv >> 1, wc = wv & 1;
  const int g = lane >> 4, q15 = lane & 15;
  const char* Ac = (const char*)A;
  const char* Bc = (const char*)B;

  f32x4 acc[4][4] = {};
  const int nK = K >> 6;
  for (int kt = 0; kt < nK; ++kt) {
    #pragma unroll
    for (int is = 0; is < 4; ++is) {
      int L = is * 4096 + wv * 1024 + lane * 16;
      int row = L >> 7, colb = L & 127;
      int src = colb ^ ((row & 7) << 4);
      gload_lds16(Ac + ((size_t)(mt * 128 + row) * K + kt * 64) * 2 + src, (char*)lA + L);
      gload_lds16(Bc + ((size_t)(nt * 128 + row) * K + kt * 64) * 2 + src, (char*)lB + L);
    }
    __syncthreads();
    #pragma unroll
    for (int kk = 0; kk < 2; ++kk) {
      bf16x8 af[4], bfr[4];
      #pragma unroll
      for (int i = 0; i < 4; ++i) {
        int ra = wr * 64 + i * 16 + q15;
        af[i] = *(const bf16x8*)((const char*)lA + ra * 128 + ((kk * 64 + g * 16) ^ ((ra & 7) << 4)));
        int rb = wc * 64 + i * 16 + q15;
        bfr[i] = *(const bf16x8*)((const char*)lB + rb * 128 + ((kk * 64 + g * 16) ^ ((rb & 7) << 4)));
      }
      #pragma unroll
      for (int i = 0; i < 4; ++i)
        #pragma unroll
        for (int j = 0; j < 4; ++j)
          acc[i][j] = __builtin_amdgcn_mfma_f32_16x16x32_bf16(af[i], bfr[j], acc[i][j], 0, 0, 0);
    }
    __syncthreads();
  }
  #pragma unroll
  for (int i = 0; i < 4; ++i) {
    int row = mt * 128 + wr * 64 + i * 16 + g * 4;
    #pragma unroll
    for (int j = 0; j < 4; ++j) {
      int col = nt * 128 + wc * 64 + j * 16 + q15;
      epi(row, col, acc[i][j]);
    }
  }
}

// ---------------- qkv GEMM with fused fp32 LoRA delta (transposed LDS) ------
// lbT stride 77 floats (odd; 77 mod 32 = 13, gcd 1 with 32) -> 16 lanes of a
// group hit 16 distinct banks on the delta ds_read_b128s (stride-76 gave 8).
__global__ __launch_bounds__(256)
void gemm_qkv(const bf16* __restrict__ A, const bf16* __restrict__ B,
              const float* __restrict__ bias, const float* __restrict__ lora_b,
              const float* __restrict__ tfF, const int* __restrict__ tfI,
              bf16* __restrict__ q, bf16* __restrict__ k, bf16* __restrict__ vT) {
  __shared__ __align__(16) char smem[39424];   // max(32768 GEMM, 128*77*4 lbT)
  bf16* lA = (bf16*)smem;
  bf16* lB = (bf16*)(smem + 16384);
  float* lbT = (float*)smem;   // [128 cols][77] fp32, reused after K-loop
  const int tid = threadIdx.x;
  const int lane = tid & 63, wv = tid >> 6;
  const int mt = blockIdx.y, nt = blockIdx.x;
  const int wr = wv >> 1, wc = wv & 1;
  const int g = lane >> 4, q15 = lane & 15;
  const char* Ac = (const char*)A;
  const char* Bc = (const char*)B;

  f32x4 acc[4][4] = {};
  for (int kt = 0; kt < 16; ++kt) {
    #pragma unroll
    for (int is = 0; is < 4; ++is) {
      int L = is * 4096 + wv * 1024 + lane * 16;
      int row = L >> 7, colb = L & 127;
      int src = colb ^ ((row & 7) << 4);
      gload_lds16(Ac + ((size_t)(mt * 128 + row) * 1024 + kt * 64) * 2 + src, (char*)lA + L);
      gload_lds16(Bc + ((size_t)(nt * 128 + row) * 1024 + kt * 64) * 2 + src, (char*)lB + L);
    }
    __syncthreads();
    #pragma unroll
    for (int kk = 0; kk < 2; ++kk) {
      bf16x8 af[4], bfr[4];
      #pragma unroll
      for (int i = 0; i < 4; ++i) {
        int ra = wr * 64 + i * 16 + q15;
        af[i] = *(const bf16x8*)((const char*)lA + ra * 128 + ((kk * 64 + g * 16) ^ ((ra & 7) << 4)));
        int rb = wc * 64 + i * 16 + q15;
        bfr[i] = *(const bf16x8*)((const char*)lB + rb * 128 + ((kk * 64 + g * 16) ^ ((rb & 7) << 4)));
      }
      #pragma unroll
      for (int i = 0; i < 4; ++i)
        #pragma unroll
        for (int j = 0; j < 4; ++j)
          acc[i][j] = __builtin_amdgcn_mfma_f32_16x16x32_bf16(af[i], bfr[j], acc[i][j], 0, 0, 0);
    }
    __syncthreads();
  }

  // stage lora_b slice transposed: lbT[c*77 + j] = lora_b[j][nt*128 + c]
  #pragma unroll
  for (int it = 0; it < 32; ++it) {
    const int flat = it * 256 + tid;
    const int j = flat >> 7, c = flat & 127;
    lbT[c * 77 + j] = lora_b[(size_t)j * 3072 + nt * 128 + c];
  }
  __syncthreads();

  #pragma unroll
  for (int i = 0; i < 4; ++i) {
    const int row = mt * 128 + wr * 64 + i * 16 + g * 4;
    #pragma unroll
    for (int r = 0; r < 4; ++r) {
      const int t = row + r;
      if (t >= TOK) continue;           // uniform within 16-lane group
      const float* tf = tfF + (size_t)t * 20;
      const float w0 = tf[0], w1 = tf[1];
      const int e0 = tfI[t * 2], e1 = tfI[t * 2 + 1];
      float4 hg0a = *(const float4*)(tf + 4);
      float4 hg0b = *(const float4*)(tf + 8);
      float4 hg1a = *(const float4*)(tf + 12);
      float4 hg1b = *(const float4*)(tf + 16);
      hg0a.x *= w0; hg0a.y *= w0; hg0a.z *= w0; hg0a.w *= w0;
      hg0b.x *= w0; hg0b.y *= w0; hg0b.z *= w0; hg0b.w *= w0;
      hg1a.x *= w1; hg1a.y *= w1; hg1a.z *= w1; hg1a.w *= w1;
      hg1b.x *= w1; hg1b.y *= w1; hg1b.z *= w1; hg1b.w *= w1;
      const int b = t / 577, n = t - b * 577;
      #pragma unroll
      for (int j = 0; j < 4; ++j) {
        const int colL = wc * 64 + j * 16 + q15;
        const int col = nt * 128 + colL;
        const float* lp = lbT + colL * 77;
        const float4 l0a = *(const float4*)(lp + e0 * 8);
        const float4 l0b = *(const float4*)(lp + e0 * 8 + 4);
        const float4 l1a = *(const float4*)(lp + e1 * 8);
        const float4 l1b = *(const float4*)(lp + e1 * 8 + 4);
        const float delta =
            hg0a.x * l0a.x + hg0a.y * l0a.y + hg0a.z * l0a.z + hg0a.w * l0a.w
          + hg0b.x * l0b.x + hg0b.y * l0b.y + hg0b.z * l0b.z + hg0b.w * l0b.w
          + hg1a.x * l1a.x + hg1a.y * l1a.y + hg1a.z * l1a.z + hg1a.w * l1a.w
          + hg1b.x * l1b.x + hg1b.y * l1b.y + hg1b.z * l1b.z + hg1b.w * l1b.w;
        const int which = col >> 10, d = col & 1023, h = d >> 6, hi = d & 63;
        const int bh = b * 16 + h;
        const float val = acc[i][j][r] + bias[col] + delta;
        if (which == 0)      q[((size_t)bh * NPAD + n) * 64 + hi] = __float2bfloat16(val * 0.125f);
        else if (which == 1) k[((size_t)bh * NPAD + n) * 64 + hi] = __float2bfloat16(val);
        else                 vT[((size_t)bh * 64 + hi) * NPAD + n] = __float2bfloat16(val);
      }
    }
  }
}

// ---------------- GEMM epilogues --------------------------------------------
struct ProjEpi {  // tok2 = tokens + attn_out @ proj^T + b
  const float* __restrict__ bias;
  const float* __restrict__ tokens;
  float* tok2;
  __device__ void operator()(int row, int col, f32x4 v) const {
    const float bs = bias[col];
    #pragma unroll
    for (int r = 0; r < 4; ++r) {
      const int t = row + r;
      if (t < TOK) tok2[(size_t)t * 1024 + col] = v[r] + bs + tokens[(size_t)t * 1024 + col];
    }
  }
};
struct Fc1Epi {  // cols<4096: gelu(x+b) [tanh form]; cols>=4096: relu(x)*g2[t][e]
  const float* __restrict__ bias;
  const float* __restrict__ g2;
  bf16* act;
  __device__ void operator()(int row, int col, f32x4 v) const {
    #pragma unroll
    for (int r = 0; r < 4; ++r) {
      const int t = row + r;
      if (t < TOK) {
        float x = v[r], val;
        if (col < 4096) {
          x += bias[col];
          const float u = 1.5957691216f * (x + 0.044715f * x * x * x);
          val = x / (1.f + __expf(-u));
        } else {
          const int e = (col - 4096) >> 6;
          val = fmaxf(x, 0.f) * g2[(size_t)t * 8 + e];
        }
        act[(size_t)t * 4608 + col] = __float2bfloat16(val);
      }
    }
  }
};
struct Fc2Epi {  // out = tok2 + (mlp + adapter) + b
  const float* __restrict__ bias;
  const float* __restrict__ tok2;
  float* out;
  __device__ void operator()(int row, int col, f32x4 v) const {
    const float bs = bias[col];
    #pragma unroll
    for (int r = 0; r < 4; ++r) {
      const int t = row + r;
      if (t < TOK)
        out[(size_t)t * 1024 + col] = v[r] + bs + tok2[(size_t)t * 1024 + col];
    }
  }
};

// ---------------- flash attention (LDS-materialized P, 64-key chunks) -------
__global__ __launch_bounds__(256)
void attn_kernel(const bf16* __restrict__ qb, const bf16* __restrict__ kb,
                 const bf16* __restrict__ vTb, bf16* __restrict__ ao) {
  __shared__ __align__(16) bf16 kls[64 * 64];
  __shared__ __align__(16) bf16 vls[64 * 64];
  __shared__ __align__(16) bf16 pls[4][16][72];  // [wave][q15][key], padded rows
  const int bid = blockIdx.x;
  const int qt = bid % 10, bh = bid / 10;
  const int b = bh >> 4, h = bh & 15;
  const int tid = threadIdx.x, lane = tid & 63, wv = tid >> 6;
  const int g = lane >> 4, q15 = lane & 15;

  const int qrow = qt * 64 + wv * 16 + q15;
  const bf16* qp = qb + ((size_t)bh * NPAD + qrow) * 64;
  const bf16x8 bq0 = *(const bf16x8*)(qp + g * 8);
  const bf16x8 bq1 = *(const bf16x8*)(qp + 32 + g * 8);

  f32x4 o[4] = {};
  float m = -1e30f, l = 0.f;

  for (int kc = 0; kc < 10; ++kc) {
    #pragma unroll
    for (int is = 0; is < 2; ++is) {
      int L = is * 4096 + wv * 1024 + lane * 16;
      int row = L >> 7, colb = L & 127;
      int src = colb ^ ((row & 7) << 4);
      gload_lds16((const char*)kb + ((size_t)(bh * NPAD + kc * 64 + row) * 64) * 2 + src, (char*)kls + L);
      gload_lds16((const char*)vTb + ((size_t)(bh * 64 + row) * NPAD + kc * 64) * 2 + src, (char*)vls + L);
    }
    __syncthreads();

    f32x4 s[4];
    __builtin_amdgcn_s_setprio(1);
    #pragma unroll
    for (int kg = 0; kg < 4; ++kg) {
      const int kr = kg * 16 + q15;
      const int sw = (kr & 7) << 4;
      const bf16x8 a0 = *(const bf16x8*)((const char*)kls + kr * 128 + ((g * 16) ^ sw));
      const bf16x8 a1 = *(const bf16x8*)((const char*)kls + kr * 128 + ((64 + g * 16) ^ sw));
      f32x4 z = {};
      z = __builtin_amdgcn_mfma_f32_16x16x32_bf16(a0, bq0, z, 0, 0, 0);
      s[kg] = __builtin_amdgcn_mfma_f32_16x16x32_bf16(a1, bq1, z, 0, 0, 0);
    }
    __builtin_amdgcn_s_setprio(0);

    float pmax = -1e30f;
    #pragma unroll
    for (int kg = 0; kg < 4; ++kg)
      #pragma unroll
      for (int r = 0; r < 4; ++r) {
        const int key = kc * 64 + kg * 16 + g * 4 + r;
        const float sv = (key < 577) ? s[kg][r] : -1e30f;
        s[kg][r] = sv;
        pmax = fmaxf(pmax, sv);
      }
    pmax = fmaxf(pmax, __shfl_xor(pmax, 16));
    pmax = fmaxf(pmax, __shfl_xor(pmax, 32));
    const float mnew = fmaxf(m, pmax);
    const float fac = __expf(m - mnew);
    float psum = 0.f;
    float p[4][4];
    #pragma unroll
    for (int kg = 0; kg < 4; ++kg)
      #pragma unroll
      for (int r = 0; r < 4; ++r) {
        p[kg][r] = __expf(s[kg][r] - mnew);
        psum += p[kg][r];
      }
    psum += __shfl_xor(psum, 16);
    psum += __shfl_xor(psum, 32);
    l = l * fac + psum;
    m = mnew;
    #pragma unroll
    for (int dg = 0; dg < 4; ++dg) {
      o[dg][0] *= fac; o[dg][1] *= fac; o[dg][2] *= fac; o[dg][3] *= fac;
    }

    #pragma unroll
    for (int kg = 0; kg < 4; ++kg)
      #pragma unroll
      for (int r = 0; r < 4; ++r)
        pls[wv][q15][kg * 16 + g * 4 + r] = __float2bfloat16(p[kg][r]);
    __syncthreads();

    __builtin_amdgcn_s_setprio(1);
    #pragma unroll
    for (int c = 0; c < 2; ++c) {
      const bf16x8 pb = *(const bf16x8*)&pls[wv][q15][c * 32 + g * 8];
      #pragma unroll
      for (int dg = 0; dg < 4; ++dg) {
        const int dr = dg * 16 + q15;
        const bf16x8 av = *(const bf16x8*)((const char*)vls + dr * 128 + ((c * 64 + g * 16) ^ ((dr & 7) << 4)));
        o[dg] = __builtin_amdgcn_mfma_f32_16x16x32_bf16(av, pb, o[dg], 0, 0, 0);
      }
    }
    __builtin_amdgcn_s_setprio(0);
    __syncthreads();
  }

  const int n = qt * 64 + wv * 16 + q15;
  if (n < 577) {
    const float inv = 1.f / l;
    const size_t trow = (size_t)b * 577 + n;
    #pragma unroll
    for (int dg = 0; dg < 4; ++dg) {
      ushort4 pk = make_ushort4(f2bu(o[dg][0] * inv), f2bu(o[dg][1] * inv),
                                f2bu(o[dg][2] * inv), f2bu(o[dg][3] * inv));
      *(ushort4*)(ao + trow * 1024 + h * 64 + dg * 16 + g * 4) = pk;
    }
  }
}

// ---------------- workspace layout ------------------------------------------
constexpr size_t SZ_WQKV  = (size_t)3072 * 1024 * 2;
constexpr size_t SZ_WPROJ = (size_t)1024 * 1024 * 2;
constexpr size_t SZ_W1    = (size_t)4608 * 1024 * 2;
constexpr size_t SZ_W2    = (size_t)1024 * 4608 * 2;
constexpr size_t SZ_TFF   = (size_t)TOK * 20 * 4;
constexpr size_t SZ_TFI   = (size_t)TOK * 2 * 4;
constexpr size_t SZ_G2    = (size_t)TOK * 8 * 4;
constexpr size_t SZ_TOK2  = (size_t)TP * 1024 * 4;
constexpr size_t SZ_MI    = (size_t)TP * 1024 * 2;
constexpr size_t SZ_N1    = (size_t)TP * 1024 * 2;
constexpr size_t SZ_QKV1  = (size_t)16 * 16 * NPAD * 64 * 2;

constexpr size_t OFF_WQKV  = 0;
constexpr size_t OFF_WPROJ = OFF_WQKV + SZ_WQKV;
constexpr size_t OFF_W1    = OFF_WPROJ + SZ_WPROJ;
constexpr size_t OFF_W2    = OFF_W1 + SZ_W1;
constexpr size_t OFF_TFF   = OFF_W2 + SZ_W2;
constexpr size_t OFF_TFI   = OFF_TFF + SZ_TFF;
constexpr size_t OFF_G2    = OFF_TFI + SZ_TFI;
constexpr size_t OFF_TOK2  = OFF_G2 + SZ_G2;
constexpr size_t OFF_MI    = OFF_TOK2 + SZ_TOK2;
constexpr size_t OFF_OVL   = OFF_MI + SZ_MI;     // n1 + q/k/vT + attnb; later act
constexpr size_t OFF_N1    = OFF_OVL;
constexpr size_t OFF_Q     = OFF_N1 + SZ_N1;
constexpr size_t OFF_K     = OFF_Q + SZ_QKV1;
constexpr size_t OFF_VT    = OFF_K + SZ_QKV1;
constexpr size_t OFF_ATT   = OFF_VT + SZ_QKV1;
constexpr size_t OFF_ACT   = OFF_OVL;            // [TP][4608] bf16 (86.1MB) fits the
                                                 // n1+q/k/vT+attnb region (~101MB)

extern "C" void kernel_launch(void* const* d_in, const int* in_sizes, int n_in,
                              void* d_out, int out_size, void* d_ws, size_t ws_size,
                              hipStream_t stream) {
  (void)in_sizes; (void)n_in; (void)out_size; (void)ws_size;
  const float* tokens    = (const float*)d_in[0];
  const float* ln1_g     = (const float*)d_in[1];
  const float* ln1_b     = (const float*)d_in[2];
  const float* ln2_g     = (const float*)d_in[3];
  const float* ln2_b     = (const float*)d_in[4];
  const float* qkv_w     = (const float*)d_in[5];
  const float* qkv_b     = (const float*)d_in[6];
  const float* proj_w    = (const float*)d_in[7];
  const float* proj_b    = (const float*)d_in[8];
  const float* fc1_w     = (const float*)d_in[9];
  const float* fc1_b     = (const float*)d_in[10];
  const float* fc2_w     = (const float*)d_in[11];
  const float* fc2_b     = (const float*)d_in[12];
  const float* lora_a    = (const float*)d_in[13];
  const float* lora_b    = (const float*)d_in[14];
  const float* lora_gate = (const float*)d_in[15];
  const float* ad_down   = (const float*)d_in[16];
  const float* ad_up     = (const float*)d_in[17];
  const float* ad_gate   = (const float*)d_in[18];
  float* out = (float*)d_out;
  char* ws = (char*)d_ws;

  bf16* wqkv  = (bf16*)(ws + OFF_WQKV);
  bf16* wproj = (bf16*)(ws + OFF_WPROJ);
  bf16* w1    = (bf16*)(ws + OFF_W1);
  bf16* w2    = (bf16*)(ws + OFF_W2);
  float* tfF  = (float*)(ws + OFF_TFF);
  int*   tfI  = (int*)(ws + OFF_TFI);
  float* g2   = (float*)(ws + OFF_G2);
  float* tok2 = (float*)(ws + OFF_TOK2);
  bf16* mi    = (bf16*)(ws + OFF_MI);
  bf16* n1    = (bf16*)(ws + OFF_N1);
  bf16* qbuf  = (bf16*)(ws + OFF_Q);
  bf16* kbuf  = (bf16*)(ws + OFF_K);
  bf16* vTbuf = (bf16*)(ws + OFF_VT);
  bf16* attnb = (bf16*)(ws + OFF_ATT);
  bf16* act   = (bf16*)(ws + OFF_ACT);

  prep_cast<<<(3072 * 1024 + 255) / 256, 256, 0, stream>>>(qkv_w, wqkv, 3072 * 1024);
  prep_cast<<<(1024 * 1024 + 255) / 256, 256, 0, stream>>>(proj_w, wproj, 1024 * 1024);
  prep_w1<<<(4608 * 1024 + 255) / 256, 256, 0, stream>>>(fc1_w, ad_down, w1);
  prep_w2<<<(1024 * 4608 + 255) / 256, 256, 0, stream>>>(fc2_w, ad_up, w2);

  ln1_kernel<<<TP, 256, 0, stream>>>(tokens, ln1_g, ln1_b, lora_gate, lora_a, n1, tfF, tfI);

  // zero q/k/vT so pad regions can never hold NaN garbage
  hipMemsetAsync(ws + OFF_Q, 0, 3 * SZ_QKV1, stream);

  gemm_qkv<<<dim3(24, 73), 256, 0, stream>>>(n1, wqkv, qkv_b, lora_b, tfF, tfI,
                                             qbuf, kbuf, vTbuf);

  attn_kernel<<<2560, 256, 0, stream>>>(qbuf, kbuf, vTbuf, attnb);

  gemm_nt<ProjEpi><<<dim3(8, 73), 256, 0, stream>>>(attnb, wproj, 1024,
      ProjEpi{proj_b, tokens, tok2});

  ln2_kernel<<<TP, 256, 0, stream>>>(tok2, ln2_g, ln2_b, ad_gate, mi, g2);

  gemm_nt<Fc1Epi><<<dim3(36, 73), 256, 0, stream>>>(mi, w1, 1024,
      Fc1Epi{fc1_b, g2, act});

  gemm_nt<Fc2Epi><<<dim3(8, 73), 256, 0, stream>>>(act, w2, 4608,
      Fc2Epi{fc2_b, tok2, out});
}

// Round 17
// 727.035 us; speedup vs baseline: 1.1522x; 1.1522x over previous
//
#include <hip/hip_runtime.h>
#include <hip/hip_bf16.h>
#include <cstdint>
#include <cstddef>

using bf16 = __hip_bfloat16;
typedef __attribute__((ext_vector_type(8))) short bf16x8;
typedef __attribute__((ext_vector_type(4))) float f32x4;

#define DEVINL __device__ __forceinline__

constexpr int TOK = 9232;   // 16*577
constexpr int TP  = 9344;   // 73*128
constexpr int NPAD = 640;   // key padding (10*64)

DEVINL unsigned short f2bu(float x) {
  union { bf16 h; unsigned short u; } cv; cv.h = __float2bfloat16(x); return cv.u;
}

DEVINL void gload_lds16(const void* g, void* l) {
  __builtin_amdgcn_global_load_lds((const __attribute__((address_space(1))) void*)g,
                                   (__attribute__((address_space(3))) void*)l, 16, 0, 0);
}

// ---------------- block reduce helper (NV values across 256 threads) --------
template <int NV>
DEVINL void blk_reduce(float* v, float* lds, int tid) {
  const int lane = tid & 63, wv = tid >> 6;
  #pragma unroll
  for (int k = 0; k < NV; ++k) {
    float x = v[k];
    x += __shfl_xor(x, 1);  x += __shfl_xor(x, 2);  x += __shfl_xor(x, 4);
    x += __shfl_xor(x, 8);  x += __shfl_xor(x, 16); x += __shfl_xor(x, 32);
    v[k] = x;
  }
  if (lane == 0) {
    #pragma unroll
    for (int k = 0; k < NV; ++k) lds[wv * NV + k] = v[k];
  }
  __syncthreads();
  #pragma unroll
  for (int k = 0; k < NV; ++k)
    v[k] = lds[k] + lds[NV + k] + lds[2 * NV + k] + lds[3 * NV + k];
  __syncthreads();
}

// ---------------- weight prep ------------------------------------------------
__global__ void prep_cast(const float* __restrict__ s, bf16* __restrict__ d, int n) {
  int i = blockIdx.x * 256 + threadIdx.x;
  if (i < n) d[i] = __float2bfloat16(s[i]);
}
// W1 aug: [4608][1024]; rows 4096+ = ad_down[e][d][bn] (row j=e*64+bn)
__global__ void prep_w1(const float* __restrict__ fc1_w, const float* __restrict__ ad_down,
                        bf16* __restrict__ W) {
  int i = blockIdx.x * 256 + threadIdx.x;
  if (i >= 4608 * 1024) return;
  int row = i >> 10, d = i & 1023;
  float v;
  if (row < 4096) v = fc1_w[(size_t)row * 1024 + d];
  else { int j = row - 4096; v = ad_down[((size_t)(j >> 6) * 1024 + d) * 64 + (j & 63)]; }
  W[i] = __float2bfloat16(v);
}
// W2 aug: [1024][4608]; cols 4096+ = ad_up[e][bn][d] (col j=e*64+bn)
__global__ void prep_w2(const float* __restrict__ fc2_w, const float* __restrict__ ad_up,
                        bf16* __restrict__ W) {
  int i = blockIdx.x * 256 + threadIdx.x;
  if (i >= 1024 * 4608) return;
  int d = i / 4608, c = i - d * 4608;
  float v;
  if (c < 4096) v = fc2_w[(size_t)d * 4096 + c];
  else { int j = c - 4096; v = ad_up[((size_t)(j >> 6) * 64 + (j & 63)) * 1024 + d]; }
  W[i] = __float2bfloat16(v);
}

// ---------------- LN1 + top2 gates + LoRA h -> n1 [TP,1024], tfF/tfI --------
// tfF layout [TOK][20]: [0]=w0 [1]=w1 [4..11]=h0 [12..19]=h1 (16B-aligned h)
__global__ __launch_bounds__(256)
void ln1_kernel(const float* __restrict__ tokens, const float* __restrict__ gw,
                const float* __restrict__ bw, const float* __restrict__ lgate,
                const float* __restrict__ lora_a, bf16* __restrict__ n1,
                float* __restrict__ tfF, int* __restrict__ tfI) {
  __shared__ float lred[64];
  __shared__ float sW[2];
  __shared__ int sI[2];
  const int t = blockIdx.x, tid = threadIdx.x;
  bf16* outr = n1 + (size_t)t * 1024;
  if (t >= TOK) {
    ((ushort4*)outr)[tid] = make_ushort4(0, 0, 0, 0);
    return;
  }
  const float4 x = ((const float4*)(tokens + (size_t)t * 1024))[tid];
  float v2[2] = { x.x + x.y + x.z + x.w, x.x * x.x + x.y * x.y + x.z * x.z + x.w * x.w };
  blk_reduce<2>(v2, lred, tid);
  const float mean = v2[0] * (1.f / 1024.f);
  const float var  = v2[1] * (1.f / 1024.f) - mean * mean;
  const float rstd = rsqrtf(var + 1e-6f);
  const float4 gg = ((const float4*)gw)[tid];
  const float4 bb = ((const float4*)bw)[tid];
  float nv[4] = { (x.x - mean) * rstd * gg.x + bb.x, (x.y - mean) * rstd * gg.y + bb.y,
                  (x.z - mean) * rstd * gg.z + bb.z, (x.w - mean) * rstd * gg.w + bb.w };
  ((ushort4*)outr)[tid] = make_ushort4(f2bu(nv[0]), f2bu(nv[1]), f2bu(nv[2]), f2bu(nv[3]));
  const int d0 = tid * 4;
  float lg[8] = {0, 0, 0, 0, 0, 0, 0, 0};
  {
    const float4* gp = (const float4*)(lgate + (size_t)d0 * 8);
    #pragma unroll
    for (int dd = 0; dd < 4; ++dd) {
      const float4 a = gp[dd * 2], c = gp[dd * 2 + 1];
      const float nd = nv[dd];
      lg[0] += nd * a.x; lg[1] += nd * a.y; lg[2] += nd * a.z; lg[3] += nd * a.w;
      lg[4] += nd * c.x; lg[5] += nd * c.y; lg[6] += nd * c.z; lg[7] += nd * c.w;
    }
  }
  blk_reduce<8>(lg, lred, tid);
  if (tid == 0) {
    float b0 = -1e30f; int i0 = 0;
    #pragma unroll
    for (int e = 0; e < 8; ++e) if (lg[e] > b0) { b0 = lg[e]; i0 = e; }
    float b1 = -1e30f; int i1 = 0;
    #pragma unroll
    for (int e = 0; e < 8; ++e) if (e != i0 && lg[e] > b1) { b1 = lg[e]; i1 = e; }
    const float e1 = __expf(b1 - b0);
    const float inv = 1.f / (1.f + e1);
    sW[0] = inv; sW[1] = e1 * inv; sI[0] = i0; sI[1] = i1;
  }
  __syncthreads();
  const int e0 = sI[0], e1i = sI[1];
  float hv[16];
  #pragma unroll
  for (int k = 0; k < 16; ++k) hv[k] = 0.f;
  #pragma unroll
  for (int ei = 0; ei < 2; ++ei) {
    const float* Ae = lora_a + (size_t)(ei == 0 ? e0 : e1i) * 8192;
    #pragma unroll
    for (int dd = 0; dd < 4; ++dd) {
      const float4* ap = (const float4*)(Ae + (size_t)(d0 + dd) * 8);
      const float4 a = ap[0], c = ap[1];
      const float nd = nv[dd];
      hv[ei * 8 + 0] += nd * a.x; hv[ei * 8 + 1] += nd * a.y;
      hv[ei * 8 + 2] += nd * a.z; hv[ei * 8 + 3] += nd * a.w;
      hv[ei * 8 + 4] += nd * c.x; hv[ei * 8 + 5] += nd * c.y;
      hv[ei * 8 + 6] += nd * c.z; hv[ei * 8 + 7] += nd * c.w;
    }
  }
  blk_reduce<16>(hv, lred, tid);
  if (tid == 0) {
    tfI[t * 2] = e0; tfI[t * 2 + 1] = e1i;
    tfF[(size_t)t * 20] = sW[0]; tfF[(size_t)t * 20 + 1] = sW[1];
  }
  if (tid < 16) tfF[(size_t)t * 20 + 4 + tid] = hv[tid];
}

// ---------------- LN2 + top2 adapter gates -> mi [TP,1024], dense g2 --------
__global__ __launch_bounds__(256)
void ln2_kernel(const float* __restrict__ tok2, const float* __restrict__ gw,
                const float* __restrict__ bw, const float* __restrict__ agate,
                bf16* __restrict__ mi, float* __restrict__ g2) {
  __shared__ float lred[64];
  __shared__ float sW[2];
  __shared__ int sI[2];
  const int t = blockIdx.x, tid = threadIdx.x;
  bf16* outr = mi + (size_t)t * 1024;
  if (t >= TOK) {
    ((ushort4*)outr)[tid] = make_ushort4(0, 0, 0, 0);
    return;
  }
  const float4 x = ((const float4*)(tok2 + (size_t)t * 1024))[tid];
  float v2[2] = { x.x + x.y + x.z + x.w, x.x * x.x + x.y * x.y + x.z * x.z + x.w * x.w };
  blk_reduce<2>(v2, lred, tid);
  const float mean = v2[0] * (1.f / 1024.f);
  const float var  = v2[1] * (1.f / 1024.f) - mean * mean;
  const float rstd = rsqrtf(var + 1e-6f);
  const float4 gg = ((const float4*)gw)[tid];
  const float4 bb = ((const float4*)bw)[tid];
  float nv[4] = { (x.x - mean) * rstd * gg.x + bb.x, (x.y - mean) * rstd * gg.y + bb.y,
                  (x.z - mean) * rstd * gg.z + bb.z, (x.w - mean) * rstd * gg.w + bb.w };
  ((ushort4*)outr)[tid] = make_ushort4(f2bu(nv[0]), f2bu(nv[1]), f2bu(nv[2]), f2bu(nv[3]));
  const int d0 = tid * 4;
  float lg[8] = {0, 0, 0, 0, 0, 0, 0, 0};
  {
    const float4* gp = (const float4*)(agate + (size_t)d0 * 8);
    #pragma unroll
    for (int dd = 0; dd < 4; ++dd) {
      const float4 a = gp[dd * 2], c = gp[dd * 2 + 1];
      const float nd = nv[dd];
      lg[0] += nd * a.x; lg[1] += nd * a.y; lg[2] += nd * a.z; lg[3] += nd * a.w;
      lg[4] += nd * c.x; lg[5] += nd * c.y; lg[6] += nd * c.z; lg[7] += nd * c.w;
    }
  }
  blk_reduce<8>(lg, lred, tid);
  if (tid == 0) {
    float b0 = -1e30f; int i0 = 0;
    #pragma unroll
    for (int e = 0; e < 8; ++e) if (lg[e] > b0) { b0 = lg[e]; i0 = e; }
    float b1 = -1e30f; int i1 = 0;
    #pragma unroll
    for (int e = 0; e < 8; ++e) if (e != i0 && lg[e] > b1) { b1 = lg[e]; i1 = e; }
    const float e1 = __expf(b1 - b0);
    const float inv = 1.f / (1.f + e1);
    sW[0] = inv; sW[1] = e1 * inv; sI[0] = i0; sI[1] = i1;
  }
  __syncthreads();
  if (tid < 8) {
    float gv = 0.f;
    if (tid == sI[0]) gv = sW[0];
    else if (tid == sI[1]) gv = sW[1];
    g2[(size_t)t * 8 + tid] = gv;
  }
}

// ---------------- 128x128 bf16 NT GEMM (m97 structure) ----------------------
template <class Epi>
__global__ __launch_bounds__(256)
void gemm_nt(const bf16* __restrict__ A, const bf16* __restrict__ B, int K, Epi epi) {
  __shared__ __align__(16) bf16 lA[128 * 64];
  __shared__ __align__(16) bf16 lB[128 * 64];
  const int tid = threadIdx.x;
  const int lane = tid & 63, wv = tid >> 6;
  const int mt = blockIdx.y, nt = blockIdx.x;
  const int wr = wv >> 1, wc = wv & 1;
  const int g = lane >> 4, q15 = lane & 15;
  const char* Ac = (const char*)A;
  const char* Bc = (const char*)B;

  f32x4 acc[4][4] = {};
  const int nK = K >> 6;
  for (int kt = 0; kt < nK; ++kt) {
    #pragma unroll
    for (int is = 0; is < 4; ++is) {
      int L = is * 4096 + wv * 1024 + lane * 16;
      int row = L >> 7, colb = L & 127;
      int src = colb ^ ((row & 7) << 4);
      gload_lds16(Ac + ((size_t)(mt * 128 + row) * K + kt * 64) * 2 + src, (char*)lA + L);
      gload_lds16(Bc + ((size_t)(nt * 128 + row) * K + kt * 64) * 2 + src, (char*)lB + L);
    }
    __syncthreads();
    #pragma unroll
    for (int kk = 0; kk < 2; ++kk) {
      bf16x8 af[4], bfr[4];
      #pragma unroll
      for (int i = 0; i < 4; ++i) {
        int ra = wr * 64 + i * 16 + q15;
        af[i] = *(const bf16x8*)((const char*)lA + ra * 128 + ((kk * 64 + g * 16) ^ ((ra & 7) << 4)));
        int rb = wc * 64 + i * 16 + q15;
        bfr[i] = *(const bf16x8*)((const char*)lB + rb * 128 + ((kk * 64 + g * 16) ^ ((rb & 7) << 4)));
      }
      #pragma unroll
      for (int i = 0; i < 4; ++i)
        #pragma unroll
        for (int j = 0; j < 4; ++j)
          acc[i][j] = __builtin_amdgcn_mfma_f32_16x16x32_bf16(af[i], bfr[j], acc[i][j], 0, 0, 0);
    }
    __syncthreads();
  }
  #pragma unroll
  for (int i = 0; i < 4; ++i) {
    int row = mt * 128 + wr * 64 + i * 16 + g * 4;
    #pragma unroll
    for (int j = 0; j < 4; ++j) {
      int col = nt * 128 + wc * 64 + j * 16 + q15;
      epi(row, col, acc[i][j]);
    }
  }
}

// ---------------- qkv GEMM with fused fp32 LoRA delta (transposed LDS) ------
// lbT stride 76 floats: 16B-aligned rows (76=4*19) keep the delta reads as
// ds_read_b128; residual bank aliasing is 2-way (free). Stride 77 (R16)
// broke 16B alignment -> scalar ds_read_b32 x4 -> 66% slower. Keep 76.
__global__ __launch_bounds__(256)
void gemm_qkv(const bf16* __restrict__ A, const bf16* __restrict__ B,
              const float* __restrict__ bias, const float* __restrict__ lora_b,
              const float* __restrict__ tfF, const int* __restrict__ tfI,
              bf16* __restrict__ q, bf16* __restrict__ k, bf16* __restrict__ vT) {
  __shared__ __align__(16) char smem[39168];   // max(32768 GEMM, 128*76*4 lbT)
  bf16* lA = (bf16*)smem;
  bf16* lB = (bf16*)(smem + 16384);
  float* lbT = (float*)smem;   // [128 cols][76] fp32, reused after K-loop
  const int tid = threadIdx.x;
  const int lane = tid & 63, wv = tid >> 6;
  const int mt = blockIdx.y, nt = blockIdx.x;
  const int wr = wv >> 1, wc = wv & 1;
  const int g = lane >> 4, q15 = lane & 15;
  const char* Ac = (const char*)A;
  const char* Bc = (const char*)B;

  f32x4 acc[4][4] = {};
  for (int kt = 0; kt < 16; ++kt) {
    #pragma unroll
    for (int is = 0; is < 4; ++is) {
      int L = is * 4096 + wv * 1024 + lane * 16;
      int row = L >> 7, colb = L & 127;
      int src = colb ^ ((row & 7) << 4);
      gload_lds16(Ac + ((size_t)(mt * 128 + row) * 1024 + kt * 64) * 2 + src, (char*)lA + L);
      gload_lds16(Bc + ((size_t)(nt * 128 + row) * 1024 + kt * 64) * 2 + src, (char*)lB + L);
    }
    __syncthreads();
    #pragma unroll
    for (int kk = 0; kk < 2; ++kk) {
      bf16x8 af[4], bfr[4];
      #pragma unroll
      for (int i = 0; i < 4; ++i) {
        int ra = wr * 64 + i * 16 + q15;
        af[i] = *(const bf16x8*)((const char*)lA + ra * 128 + ((kk * 64 + g * 16) ^ ((ra & 7) << 4)));
        int rb = wc * 64 + i * 16 + q15;
        bfr[i] = *(const bf16x8*)((const char*)lB + rb * 128 + ((kk * 64 + g * 16) ^ ((rb & 7) << 4)));
      }
      #pragma unroll
      for (int i = 0; i < 4; ++i)
        #pragma unroll
        for (int j = 0; j < 4; ++j)
          acc[i][j] = __builtin_amdgcn_mfma_f32_16x16x32_bf16(af[i], bfr[j], acc[i][j], 0, 0, 0);
    }
    __syncthreads();
  }

  // stage lora_b slice transposed: lbT[c*76 + j] = lora_b[j][nt*128 + c]
  #pragma unroll
  for (int it = 0; it < 32; ++it) {
    const int flat = it * 256 + tid;
    const int j = flat >> 7, c = flat & 127;
    lbT[c * 76 + j] = lora_b[(size_t)j * 3072 + nt * 128 + c];
  }
  __syncthreads();

  #pragma unroll
  for (int i = 0; i < 4; ++i) {
    const int row = mt * 128 + wr * 64 + i * 16 + g * 4;
    #pragma unroll
    for (int r = 0; r < 4; ++r) {
      const int t = row + r;
      if (t >= TOK) continue;           // uniform within 16-lane group
      const float* tf = tfF + (size_t)t * 20;
      const float w0 = tf[0], w1 = tf[1];
      const int e0 = tfI[t * 2], e1 = tfI[t * 2 + 1];
      float4 hg0a = *(const float4*)(tf + 4);
      float4 hg0b = *(const float4*)(tf + 8);
      float4 hg1a = *(const float4*)(tf + 12);
      float4 hg1b = *(const float4*)(tf + 16);
      hg0a.x *= w0; hg0a.y *= w0; hg0a.z *= w0; hg0a.w *= w0;
      hg0b.x *= w0; hg0b.y *= w0; hg0b.z *= w0; hg0b.w *= w0;
      hg1a.x *= w1; hg1a.y *= w1; hg1a.z *= w1; hg1a.w *= w1;
      hg1b.x *= w1; hg1b.y *= w1; hg1b.z *= w1; hg1b.w *= w1;
      const int b = t / 577, n = t - b * 577;
      #pragma unroll
      for (int j = 0; j < 4; ++j) {
        const int colL = wc * 64 + j * 16 + q15;
        const int col = nt * 128 + colL;
        const float* lp = lbT + colL * 76;
        const float4 l0a = *(const float4*)(lp + e0 * 8);
        const float4 l0b = *(const float4*)(lp + e0 * 8 + 4);
        const float4 l1a = *(const float4*)(lp + e1 * 8);
        const float4 l1b = *(const float4*)(lp + e1 * 8 + 4);
        const float delta =
            hg0a.x * l0a.x + hg0a.y * l0a.y + hg0a.z * l0a.z + hg0a.w * l0a.w
          + hg0b.x * l0b.x + hg0b.y * l0b.y + hg0b.z * l0b.z + hg0b.w * l0b.w
          + hg1a.x * l1a.x + hg1a.y * l1a.y + hg1a.z * l1a.z + hg1a.w * l1a.w
          + hg1b.x * l1b.x + hg1b.y * l1b.y + hg1b.z * l1b.z + hg1b.w * l1b.w;
        const int which = col >> 10, d = col & 1023, h = d >> 6, hi = d & 63;
        const int bh = b * 16 + h;
        const float val = acc[i][j][r] + bias[col] + delta;
        if (which == 0)      q[((size_t)bh * NPAD + n) * 64 + hi] = __float2bfloat16(val * 0.125f);
        else if (which == 1) k[((size_t)bh * NPAD + n) * 64 + hi] = __float2bfloat16(val);
        else                 vT[((size_t)bh * 64 + hi) * NPAD + n] = __float2bfloat16(val);
      }
    }
  }
}

// ---------------- GEMM epilogues --------------------------------------------
struct ProjEpi {  // tok2 = tokens + attn_out @ proj^T + b
  const float* __restrict__ bias;
  const float* __restrict__ tokens;
  float* tok2;
  __device__ void operator()(int row, int col, f32x4 v) const {
    const float bs = bias[col];
    #pragma unroll
    for (int r = 0; r < 4; ++r) {
      const int t = row + r;
      if (t < TOK) tok2[(size_t)t * 1024 + col] = v[r] + bs + tokens[(size_t)t * 1024 + col];
    }
  }
};
struct Fc1Epi {  // cols<4096: gelu(x+b) [tanh form]; cols>=4096: relu(x)*g2[t][e]
  const float* __restrict__ bias;
  const float* __restrict__ g2;
  bf16* act;
  __device__ void operator()(int row, int col, f32x4 v) const {
    #pragma unroll
    for (int r = 0; r < 4; ++r) {
      const int t = row + r;
      if (t < TOK) {
        float x = v[r], val;
        if (col < 4096) {
          x += bias[col];
          const float u = 1.5957691216f * (x + 0.044715f * x * x * x);
          val = x / (1.f + __expf(-u));
        } else {
          const int e = (col - 4096) >> 6;
          val = fmaxf(x, 0.f) * g2[(size_t)t * 8 + e];
        }
        act[(size_t)t * 4608 + col] = __float2bfloat16(val);
      }
    }
  }
};
struct Fc2Epi {  // out = tok2 + (mlp + adapter) + b
  const float* __restrict__ bias;
  const float* __restrict__ tok2;
  float* out;
  __device__ void operator()(int row, int col, f32x4 v) const {
    const float bs = bias[col];
    #pragma unroll
    for (int r = 0; r < 4; ++r) {
      const int t = row + r;
      if (t < TOK)
        out[(size_t)t * 1024 + col] = v[r] + bs + tok2[(size_t)t * 1024 + col];
    }
  }
};

// ---------------- flash attention (LDS-materialized P, 64-key chunks) -------
__global__ __launch_bounds__(256)
void attn_kernel(const bf16* __restrict__ qb, const bf16* __restrict__ kb,
                 const bf16* __restrict__ vTb, bf16* __restrict__ ao) {
  __shared__ __align__(16) bf16 kls[64 * 64];
  __shared__ __align__(16) bf16 vls[64 * 64];
  __shared__ __align__(16) bf16 pls[4][16][72];  // [wave][q15][key], padded rows
  const int bid = blockIdx.x;
  const int qt = bid % 10, bh = bid / 10;
  const int b = bh >> 4, h = bh & 15;
  const int tid = threadIdx.x, lane = tid & 63, wv = tid >> 6;
  const int g = lane >> 4, q15 = lane & 15;

  const int qrow = qt * 64 + wv * 16 + q15;
  const bf16* qp = qb + ((size_t)bh * NPAD + qrow) * 64;
  const bf16x8 bq0 = *(const bf16x8*)(qp + g * 8);
  const bf16x8 bq1 = *(const bf16x8*)(qp + 32 + g * 8);

  f32x4 o[4] = {};
  float m = -1e30f, l = 0.f;

  for (int kc = 0; kc < 10; ++kc) {
    #pragma unroll
    for (int is = 0; is < 2; ++is) {
      int L = is * 4096 + wv * 1024 + lane * 16;
      int row = L >> 7, colb = L & 127;
      int src = colb ^ ((row & 7) << 4);
      gload_lds16((const char*)kb + ((size_t)(bh * NPAD + kc * 64 + row) * 64) * 2 + src, (char*)kls + L);
      gload_lds16((const char*)vTb + ((size_t)(bh * 64 + row) * NPAD + kc * 64) * 2 + src, (char*)vls + L);
    }
    __syncthreads();

    f32x4 s[4];
    __builtin_amdgcn_s_setprio(1);
    #pragma unroll
    for (int kg = 0; kg < 4; ++kg) {
      const int kr = kg * 16 + q15;
      const int sw = (kr & 7) << 4;
      const bf16x8 a0 = *(const bf16x8*)((const char*)kls + kr * 128 + ((g * 16) ^ sw));
      const bf16x8 a1 = *(const bf16x8*)((const char*)kls + kr * 128 + ((64 + g * 16) ^ sw));
      f32x4 z = {};
      z = __builtin_amdgcn_mfma_f32_16x16x32_bf16(a0, bq0, z, 0, 0, 0);
      s[kg] = __builtin_amdgcn_mfma_f32_16x16x32_bf16(a1, bq1, z, 0, 0, 0);
    }
    __builtin_amdgcn_s_setprio(0);

    float pmax = -1e30f;
    #pragma unroll
    for (int kg = 0; kg < 4; ++kg)
      #pragma unroll
      for (int r = 0; r < 4; ++r) {
        const int key = kc * 64 + kg * 16 + g * 4 + r;
        const float sv = (key < 577) ? s[kg][r] : -1e30f;
        s[kg][r] = sv;
        pmax = fmaxf(pmax, sv);
      }
    pmax = fmaxf(pmax, __shfl_xor(pmax, 16));
    pmax = fmaxf(pmax, __shfl_xor(pmax, 32));
    const float mnew = fmaxf(m, pmax);
    const float fac = __expf(m - mnew);
    float psum = 0.f;
    float p[4][4];
    #pragma unroll
    for (int kg = 0; kg < 4; ++kg)
      #pragma unroll
      for (int r = 0; r < 4; ++r) {
        p[kg][r] = __expf(s[kg][r] - mnew);
        psum += p[kg][r];
      }
    psum += __shfl_xor(psum, 16);
    psum += __shfl_xor(psum, 32);
    l = l * fac + psum;
    m = mnew;
    #pragma unroll
    for (int dg = 0; dg < 4; ++dg) {
      o[dg][0] *= fac; o[dg][1] *= fac; o[dg][2] *= fac; o[dg][3] *= fac;
    }

    #pragma unroll
    for (int kg = 0; kg < 4; ++kg)
      #pragma unroll
      for (int r = 0; r < 4; ++r)
        pls[wv][q15][kg * 16 + g * 4 + r] = __float2bfloat16(p[kg][r]);
    __syncthreads();

    __builtin_amdgcn_s_setprio(1);
    #pragma unroll
    for (int c = 0; c < 2; ++c) {
      const bf16x8 pb = *(const bf16x8*)&pls[wv][q15][c * 32 + g * 8];
      #pragma unroll
      for (int dg = 0; dg < 4; ++dg) {
        const int dr = dg * 16 + q15;
        const bf16x8 av = *(const bf16x8*)((const char*)vls + dr * 128 + ((c * 64 + g * 16) ^ ((dr & 7) << 4)));
        o[dg] = __builtin_amdgcn_mfma_f32_16x16x32_bf16(av, pb, o[dg], 0, 0, 0);
      }
    }
    __builtin_amdgcn_s_setprio(0);
    __syncthreads();
  }

  const int n = qt * 64 + wv * 16 + q15;
  if (n < 577) {
    const float inv = 1.f / l;
    const size_t trow = (size_t)b * 577 + n;
    #pragma unroll
    for (int dg = 0; dg < 4; ++dg) {
      ushort4 pk = make_ushort4(f2bu(o[dg][0] * inv), f2bu(o[dg][1] * inv),
                                f2bu(o[dg][2] * inv), f2bu(o[dg][3] * inv));
      *(ushort4*)(ao + trow * 1024 + h * 64 + dg * 16 + g * 4) = pk;
    }
  }
}

// ---------------- workspace layout ------------------------------------------
constexpr size_t SZ_WQKV  = (size_t)3072 * 1024 * 2;
constexpr size_t SZ_WPROJ = (size_t)1024 * 1024 * 2;
constexpr size_t SZ_W1    = (size_t)4608 * 1024 * 2;
constexpr size_t SZ_W2    = (size_t)1024 * 4608 * 2;
constexpr size_t SZ_TFF   = (size_t)TOK * 20 * 4;
constexpr size_t SZ_TFI   = (size_t)TOK * 2 * 4;
constexpr size_t SZ_G2    = (size_t)TOK * 8 * 4;
constexpr size_t SZ_TOK2  = (size_t)TP * 1024 * 4;
constexpr size_t SZ_MI    = (size_t)TP * 1024 * 2;
constexpr size_t SZ_N1    = (size_t)TP * 1024 * 2;
constexpr size_t SZ_QKV1  = (size_t)16 * 16 * NPAD * 64 * 2;

constexpr size_t OFF_WQKV  = 0;
constexpr size_t OFF_WPROJ = OFF_WQKV + SZ_WQKV;
constexpr size_t OFF_W1    = OFF_WPROJ + SZ_WPROJ;
constexpr size_t OFF_W2    = OFF_W1 + SZ_W1;
constexpr size_t OFF_TFF   = OFF_W2 + SZ_W2;
constexpr size_t OFF_TFI   = OFF_TFF + SZ_TFF;
constexpr size_t OFF_G2    = OFF_TFI + SZ_TFI;
constexpr size_t OFF_TOK2  = OFF_G2 + SZ_G2;
constexpr size_t OFF_MI    = OFF_TOK2 + SZ_TOK2;
constexpr size_t OFF_OVL   = OFF_MI + SZ_MI;     // n1 + q/k/vT + attnb; later act
constexpr size_t OFF_N1    = OFF_OVL;
constexpr size_t OFF_Q     = OFF_N1 + SZ_N1;
constexpr size_t OFF_K     = OFF_Q + SZ_QKV1;
constexpr size_t OFF_VT    = OFF_K + SZ_QKV1;
constexpr size_t OFF_ATT   = OFF_VT + SZ_QKV1;
constexpr size_t OFF_ACT   = OFF_OVL;            // [TP][4608] bf16 (86.1MB) fits the
                                                 // n1+q/k/vT+attnb region (~101MB)

extern "C" void kernel_launch(void* const* d_in, const int* in_sizes, int n_in,
                              void* d_out, int out_size, void* d_ws, size_t ws_size,
                              hipStream_t stream) {
  (void)in_sizes; (void)n_in; (void)out_size; (void)ws_size;
  const float* tokens    = (const float*)d_in[0];
  const float* ln1_g     = (const float*)d_in[1];
  const float* ln1_b     = (const float*)d_in[2];
  const float* ln2_g     = (const float*)d_in[3];
  const float* ln2_b     = (const float*)d_in[4];
  const float* qkv_w     = (const float*)d_in[5];
  const float* qkv_b     = (const float*)d_in[6];
  const float* proj_w    = (const float*)d_in[7];
  const float* proj_b    = (const float*)d_in[8];
  const float* fc1_w     = (const float*)d_in[9];
  const float* fc1_b     = (const float*)d_in[10];
  const float* fc2_w     = (const float*)d_in[11];
  const float* fc2_b     = (const float*)d_in[12];
  const float* lora_a    = (const float*)d_in[13];
  const float* lora_b    = (const float*)d_in[14];
  const float* lora_gate = (const float*)d_in[15];
  const float* ad_down   = (const float*)d_in[16];
  const float* ad_up     = (const float*)d_in[17];
  const float* ad_gate   = (const float*)d_in[18];
  float* out = (float*)d_out;
  char* ws = (char*)d_ws;

  bf16* wqkv  = (bf16*)(ws + OFF_WQKV);
  bf16* wproj = (bf16*)(ws + OFF_WPROJ);
  bf16* w1    = (bf16*)(ws + OFF_W1);
  bf16* w2    = (bf16*)(ws + OFF_W2);
  float* tfF  = (float*)(ws + OFF_TFF);
  int*   tfI  = (int*)(ws + OFF_TFI);
  float* g2   = (float*)(ws + OFF_G2);
  float* tok2 = (float*)(ws + OFF_TOK2);
  bf16* mi    = (bf16*)(ws + OFF_MI);
  bf16* n1    = (bf16*)(ws + OFF_N1);
  bf16* qbuf  = (bf16*)(ws + OFF_Q);
  bf16* kbuf  = (bf16*)(ws + OFF_K);
  bf16* vTbuf = (bf16*)(ws + OFF_VT);
  bf16* attnb = (bf16*)(ws + OFF_ATT);
  bf16* act   = (bf16*)(ws + OFF_ACT);

  prep_cast<<<(3072 * 1024 + 255) / 256, 256, 0, stream>>>(qkv_w, wqkv, 3072 * 1024);
  prep_cast<<<(1024 * 1024 + 255) / 256, 256, 0, stream>>>(proj_w, wproj, 1024 * 1024);
  prep_w1<<<(4608 * 1024 + 255) / 256, 256, 0, stream>>>(fc1_w, ad_down, w1);
  prep_w2<<<(1024 * 4608 + 255) / 256, 256, 0, stream>>>(fc2_w, ad_up, w2);

  ln1_kernel<<<TP, 256, 0, stream>>>(tokens, ln1_g, ln1_b, lora_gate, lora_a, n1, tfF, tfI);

  // zero q/k/vT so pad regions can never hold NaN garbage
  hipMemsetAsync(ws + OFF_Q, 0, 3 * SZ_QKV1, stream);

  gemm_qkv<<<dim3(24, 73), 256, 0, stream>>>(n1, wqkv, qkv_b, lora_b, tfF, tfI,
                                             qbuf, kbuf, vTbuf);

  attn_kernel<<<2560, 256, 0, stream>>>(qbuf, kbuf, vTbuf, attnb);

  gemm_nt<ProjEpi><<<dim3(8, 73), 256, 0, stream>>>(attnb, wproj, 1024,
      ProjEpi{proj_b, tokens, tok2});

  ln2_kernel<<<TP, 256, 0, stream>>>(tok2, ln2_g, ln2_b, ad_gate, mi, g2);

  gemm_nt<Fc1Epi><<<dim3(36, 73), 256, 0, stream>>>(mi, w1, 1024,
      Fc1Epi{fc1_b, g2, act});

  gemm_nt<Fc2Epi><<<dim3(8, 73), 256, 0, stream>>>(act, w2, 4608,
      Fc2Epi{fc2_b, tok2, out});
}